// Round 1
// baseline (8329.757 us; speedup 1.0000x reference)
//
#include <hip/hip_runtime.h>

typedef unsigned short u16;
typedef __attribute__((ext_vector_type(8))) short short8;      // 8 bf16 (4 VGPRs) MFMA operand
typedef __attribute__((ext_vector_type(8))) unsigned short u16x8;
typedef __attribute__((ext_vector_type(4))) unsigned short u16x4;
typedef __attribute__((ext_vector_type(4))) float floatx4;

#define L_LAYERS 22
#define D_MODEL 768
#define N_HEADS 12
#define HEAD_D 64
#define I_FF 1152
#define B_BATCH 8
#define S_SEQ 1024
#define M_ROWS (B_BATCH * S_SEQ)   // 8192

__device__ __forceinline__ u16 f2bf(float f) {
    union { float f; unsigned u; } v; v.f = f;
    unsigned r = v.u + 0x7fffu + ((v.u >> 16) & 1u);  // RNE
    return (u16)(r >> 16);
}

// ---------------------------------------------------------------------------
__global__ __launch_bounds__(256) void rope_tables_kernel(float* cg, float* sg, float* cl, float* sl) {
    int i = blockIdx.x * 256 + threadIdx.x;
    if (i >= 1024 * 32) return;
    int s = i >> 5, j = i & 31;
    float e = (float)(2 * j) / 64.f;
    float fg = (float)s * powf(160000.f, -e);
    float fl = (float)s * powf(10000.f, -e);
    cg[i] = cosf(fg); sg[i] = sinf(fg);
    cl[i] = cosf(fl); sl[i] = sinf(fl);
}

// ---------------------------------------------------------------------------
__global__ __launch_bounds__(256) void embed_ln_kernel(const int* __restrict__ ids,
                                                       const float* __restrict__ emb,
                                                       const float* __restrict__ w,
                                                       float* __restrict__ x,
                                                       u16* __restrict__ hbf) {
    int tok = blockIdx.x;
    int tid = threadIdx.x;
    const float* row = emb + (size_t)ids[tok] * D_MODEL;
    float v[3]; float s = 0.f, q = 0.f;
#pragma unroll
    for (int i = 0; i < 3; ++i) { v[i] = row[tid + 256 * i]; s += v[i]; q += v[i] * v[i]; }
#pragma unroll
    for (int o = 32; o; o >>= 1) { s += __shfl_down(s, o); q += __shfl_down(q, o); }
    __shared__ float rs[4], rq[4];
    int wid = tid >> 6, lane = tid & 63;
    if (!lane) { rs[wid] = s; rq[wid] = q; }
    __syncthreads();
    s = rs[0] + rs[1] + rs[2] + rs[3]; q = rq[0] + rq[1] + rq[2] + rq[3];
    float mean = s * (1.f / 768.f);
    float var = q * (1.f / 768.f) - mean * mean;
    float rstd = rsqrtf(var + 1e-5f);
#pragma unroll
    for (int i = 0; i < 3; ++i) {
        float y = (v[i] - mean) * rstd * w[tid + 256 * i];
        x[(size_t)tok * D_MODEL + tid + 256 * i] = y;
        hbf[(size_t)tok * D_MODEL + tid + 256 * i] = f2bf(y);
    }
}

__global__ __launch_bounds__(256) void ln_kernel(const float* __restrict__ x,
                                                 const float* __restrict__ w,
                                                 u16* __restrict__ out_bf,
                                                 float* __restrict__ out_f32) {
    int tok = blockIdx.x;
    int tid = threadIdx.x;
    const float* row = x + (size_t)tok * D_MODEL;
    float v[3]; float s = 0.f, q = 0.f;
#pragma unroll
    for (int i = 0; i < 3; ++i) { v[i] = row[tid + 256 * i]; s += v[i]; q += v[i] * v[i]; }
#pragma unroll
    for (int o = 32; o; o >>= 1) { s += __shfl_down(s, o); q += __shfl_down(q, o); }
    __shared__ float rs[4], rq[4];
    int wid = tid >> 6, lane = tid & 63;
    if (!lane) { rs[wid] = s; rq[wid] = q; }
    __syncthreads();
    s = rs[0] + rs[1] + rs[2] + rs[3]; q = rq[0] + rq[1] + rq[2] + rq[3];
    float mean = s * (1.f / 768.f);
    float var = q * (1.f / 768.f) - mean * mean;
    float rstd = rsqrtf(var + 1e-5f);
#pragma unroll
    for (int i = 0; i < 3; ++i) {
        float y = (v[i] - mean) * rstd * w[tid + 256 * i];
        if (out_bf)  out_bf[(size_t)tok * D_MODEL + tid + 256 * i] = f2bf(y);
        if (out_f32) out_f32[(size_t)tok * D_MODEL + tid + 256 * i] = y;
    }
}

// ---------------------------------------------------------------------------
__global__ __launch_bounds__(256) void transpose_cast_kernel(const float* __restrict__ in,
                                                             u16* __restrict__ out,
                                                             int Kw, int Nw) {
    __shared__ float tile[32][33];
    int c0 = blockIdx.x * 32, r0 = blockIdx.y * 32;
    int tc = threadIdx.x & 31, tr = threadIdx.x >> 5;
#pragma unroll
    for (int i = 0; i < 4; ++i) {
        int r = tr + i * 8;
        tile[r][tc] = in[(size_t)(r0 + r) * Nw + c0 + tc];
    }
    __syncthreads();
#pragma unroll
    for (int i = 0; i < 4; ++i) {
        int r = tr + i * 8;
        out[(size_t)(c0 + r) * Kw + r0 + tc] = f2bf(tile[tc][r]);
    }
}

// ---------------------------------------------------------------------------
__global__ __launch_bounds__(256) void gemm_nt_kernel(const u16* __restrict__ A,
                                                      const u16* __restrict__ B,
                                                      const float* R,
                                                      float* C,
                                                      int M, int N, int K) {
    __shared__ u16 As[128][40];
    __shared__ u16 Bs[128][40];
    int tid = threadIdx.x;
    int lane = tid & 63, wid = tid >> 6;
    int lr = lane & 15, lg = lane >> 4;
    int bm = blockIdx.y * 128, bn = blockIdx.x * 128;
    int wr = (wid >> 1) * 64, wc = (wid & 1) * 64;
    floatx4 acc[4][4] = {};
    for (int k0 = 0; k0 < K; k0 += 32) {
        __syncthreads();
#pragma unroll
        for (int i = 0; i < 2; ++i) {
            int flat = tid + i * 256;
            int row = flat >> 2, c8 = (flat & 3) * 8;
            *(u16x8*)&As[row][c8] = *(const u16x8*)(A + (size_t)(bm + row) * K + k0 + c8);
            *(u16x8*)&Bs[row][c8] = *(const u16x8*)(B + (size_t)(bn + row) * K + k0 + c8);
        }
        __syncthreads();
        short8 af[4], bfr[4];
#pragma unroll
        for (int t = 0; t < 4; ++t) {
            af[t]  = *(const short8*)&As[wr + t * 16 + lr][lg * 8];
            bfr[t] = *(const short8*)&Bs[wc + t * 16 + lr][lg * 8];
        }
#pragma unroll
        for (int mi = 0; mi < 4; ++mi)
#pragma unroll
            for (int ni = 0; ni < 4; ++ni)
                acc[mi][ni] = __builtin_amdgcn_mfma_f32_16x16x32_bf16(af[mi], bfr[ni], acc[mi][ni], 0, 0, 0);
    }
#pragma unroll
    for (int mi = 0; mi < 4; ++mi) {
        int m = bm + wr + mi * 16 + lg * 4;
#pragma unroll
        for (int ni = 0; ni < 4; ++ni) {
            int n = bn + wc + ni * 16 + lr;
#pragma unroll
            for (int r = 0; r < 4; ++r) {
                float v = acc[mi][ni][r];
                size_t idx = (size_t)(m + r) * N + n;
                if (R) v += R[idx];
                C[idx] = v;
            }
        }
    }
}

// ---------------------------------------------------------------------------
__global__ __launch_bounds__(256) void rope_qk_kernel(const float* __restrict__ qkv,
                                                      const float* __restrict__ cosT,
                                                      const float* __restrict__ sinT,
                                                      u16* __restrict__ Q,
                                                      u16* __restrict__ K) {
    int tok = blockIdx.x;
    int b = tok >> 10, s = tok & 1023;
    const float* base = qkv + (size_t)tok * 2304;
    for (int p = threadIdx.x; p < 384; p += 256) {
        int h = p >> 5, j = p & 31;
        float c = cosT[s * 32 + j], sn = sinT[s * 32 + j];
        size_t off = ((size_t)(b * N_HEADS + h) * S_SEQ + s) * HEAD_D + j;
        float q1 = base[h * 64 + j], q2 = base[h * 64 + j + 32];
        Q[off]      = f2bf(q1 * c - q2 * sn);
        Q[off + 32] = f2bf(q2 * c + q1 * sn);
        float k1 = base[768 + h * 64 + j], k2 = base[768 + h * 64 + j + 32];
        K[off]      = f2bf(k1 * c - k2 * sn);
        K[off + 32] = f2bf(k2 * c + k1 * sn);
    }
}

__global__ __launch_bounds__(256) void v_trans_kernel(const float* __restrict__ qkv,
                                                      u16* __restrict__ Vt) {
    __shared__ u16 tile[64][65];
    int bh = blockIdx.y;
    int b = bh / 12, h = bh - b * 12;
    int s0 = blockIdx.x * 64;
    int d = threadIdx.x & 63, si0 = threadIdx.x >> 6;
#pragma unroll
    for (int i = 0; i < 16; ++i) {
        int si = si0 + i * 4;
        tile[si][d] = f2bf(qkv[((size_t)(b * S_SEQ + s0 + si)) * 2304 + 1536 + h * 64 + d]);
    }
    __syncthreads();
    int si = threadIdx.x & 63, dd0 = threadIdx.x >> 6;
#pragma unroll
    for (int i = 0; i < 16; ++i) {
        int dd = dd0 + i * 4;
        Vt[((size_t)bh * 64 + dd) * S_SEQ + s0 + si] = tile[si][dd];
    }
}

// ---------------------------------------------------------------------------
__global__ __launch_bounds__(256) void flash_attn_kernel(const u16* __restrict__ Q,
                                                         const u16* __restrict__ Kb,
                                                         const u16* __restrict__ Vt,
                                                         u16* __restrict__ O,
                                                         int is_local) {
    __shared__ u16 Pl[4][16][40];
    int bh = blockIdx.y;
    int b = bh / 12, h = bh - b * 12;
    int qb0 = blockIdx.x * 64;
    int tid = threadIdx.x, lane = tid & 63, wid = tid >> 6;
    int lr = lane & 15, lg = lane >> 4;
    int q_row = qb0 + wid * 16 + lr;
    const u16* Qrow = Q + ((size_t)bh * S_SEQ + q_row) * HEAD_D + lg * 8;
    short8 qf0 = *(const short8*)Qrow;
    short8 qf1 = *(const short8*)(Qrow + 32);
    floatx4 accO[4] = {};
    float m_run = -1e30f, l_run = 0.f;
    int kstart = 0, kend = S_SEQ;
    if (is_local) {
        kstart = qb0 - 64; if (kstart < 0) kstart = 0;
        kend = qb0 + 128; if (kend > S_SEQ) kend = S_SEQ;
    }
    for (int k0 = kstart; k0 < kend; k0 += 32) {
        floatx4 sA = {}, sB = {};
        {
            const u16* Kp = Kb + ((size_t)bh * S_SEQ + k0 + lr) * HEAD_D + lg * 8;
            short8 kf0 = *(const short8*)Kp;
            short8 kf1 = *(const short8*)(Kp + 32);
            sA = __builtin_amdgcn_mfma_f32_16x16x32_bf16(kf0, qf0, sA, 0, 0, 0);
            sA = __builtin_amdgcn_mfma_f32_16x16x32_bf16(kf1, qf1, sA, 0, 0, 0);
            const u16* Kp2 = Kp + 16 * HEAD_D;
            short8 kg0 = *(const short8*)Kp2;
            short8 kg1 = *(const short8*)(Kp2 + 32);
            sB = __builtin_amdgcn_mfma_f32_16x16x32_bf16(kg0, qf0, sB, 0, 0, 0);
            sB = __builtin_amdgcn_mfma_f32_16x16x32_bf16(kg1, qf1, sB, 0, 0, 0);
        }
        float sv[8]; float mloc = -1e30f;
#pragma unroll
        for (int r = 0; r < 4; ++r) {
            int kposA = k0 + lg * 4 + r;
            float s1 = sA[r] * 0.125f;
            int dA = q_row - kposA; if (dA < 0) dA = -dA;
            if (is_local && dA > 64) s1 = -1e9f;
            sv[r] = s1; mloc = fmaxf(mloc, s1);
            int kposB = kposA + 16;
            float s2 = sB[r] * 0.125f;
            int dB = q_row - kposB; if (dB < 0) dB = -dB;
            if (is_local && dB > 64) s2 = -1e9f;
            sv[4 + r] = s2; mloc = fmaxf(mloc, s2);
        }
        mloc = fmaxf(mloc, __shfl_xor(mloc, 16));
        mloc = fmaxf(mloc, __shfl_xor(mloc, 32));
        float m_new = fmaxf(m_run, mloc);
        float alpha = __expf(m_run - m_new);
        float psum = 0.f;
        u16 pu[8];
#pragma unroll
        for (int i = 0; i < 8; ++i) {
            float p = __expf(sv[i] - m_new);
            psum += p; pu[i] = f2bf(p);
        }
        psum += __shfl_xor(psum, 16);
        psum += __shfl_xor(psum, 32);
        l_run = l_run * alpha + psum;
        m_run = m_new;
#pragma unroll
        for (int c = 0; c < 4; ++c)
#pragma unroll
            for (int r = 0; r < 4; ++r) accO[c][r] *= alpha;
        u16x4 w0 = { pu[0], pu[1], pu[2], pu[3] };
        u16x4 w1 = { pu[4], pu[5], pu[6], pu[7] };
        *(u16x4*)&Pl[wid][lr][lg * 4] = w0;
        *(u16x4*)&Pl[wid][lr][16 + lg * 4] = w1;
        asm volatile("s_waitcnt lgkmcnt(0)" ::: "memory");
        __builtin_amdgcn_sched_barrier(0);
        short8 pf = *(const short8*)&Pl[wid][lr][lg * 8];
#pragma unroll
        for (int c = 0; c < 4; ++c) {
            const u16* Vp = Vt + ((size_t)bh * 64 + c * 16 + lr) * S_SEQ + k0 + lg * 8;
            short8 vf = *(const short8*)Vp;
            accO[c] = __builtin_amdgcn_mfma_f32_16x16x32_bf16(vf, pf, accO[c], 0, 0, 0);
        }
    }
    float inv_l = 1.0f / l_run;
#pragma unroll
    for (int c = 0; c < 4; ++c)
#pragma unroll
        for (int r = 0; r < 4; ++r) {
            int d = c * 16 + lg * 4 + r;
            O[((size_t)b * S_SEQ + q_row) * D_MODEL + h * 64 + d] = f2bf(accO[c][r] * inv_l);
        }
}

// ---------------------------------------------------------------------------
__global__ __launch_bounds__(256) void geglu_kernel(const float* __restrict__ a,
                                                    u16* __restrict__ g) {
    int idx = blockIdx.x * 256 + threadIdx.x;
    int m = idx / 288;
    int i4 = (idx - m * 288) * 4;
    const float* arow = a + (size_t)m * 2304;
    floatx4 xi = *(const floatx4*)(arow + i4);
    floatx4 xg = *(const floatx4*)(arow + 1152 + i4);
    u16x4 r;
#pragma unroll
    for (int j = 0; j < 4; ++j) {
        float v = xi[j];
        float ge = 0.5f * v * (1.f + erff(v * 0.70710678118654752f));
        r[j] = f2bf(ge * xg[j]);
    }
    *(u16x4*)(g + (size_t)m * I_FF + i4) = r;
}

// ---------------------------------------------------------------------------
__global__ __launch_bounds__(256) void pool_kernel(const float* __restrict__ xln,
                                                   const int* __restrict__ amask,
                                                   float* __restrict__ pooled) {
    int b = blockIdx.y;
    int d = blockIdx.x * 256 + threadIdx.x;
    float acc = 0.f, cnt = 0.f;
    for (int s = 0; s < S_SEQ; ++s) {
        float m = (float)amask[b * S_SEQ + s];
        acc += xln[((size_t)b * S_SEQ + s) * D_MODEL + d] * m;
        cnt += m;
    }
    pooled[b * D_MODEL + d] = acc / fmaxf(cnt, 1e-9f);
}

__global__ __launch_bounds__(256) void logits_kernel(const float* __restrict__ pooled,
                                                     const float* __restrict__ cls_w,
                                                     const float* __restrict__ cls_b,
                                                     float* __restrict__ out) {
    int b = blockIdx.x;
    float p = 0.f;
    for (int d = threadIdx.x; d < D_MODEL; d += 256) p += pooled[b * D_MODEL + d] * cls_w[d];
#pragma unroll
    for (int o = 32; o; o >>= 1) p += __shfl_down(p, o);
    __shared__ float r[4];
    int wid = threadIdx.x >> 6, lane = threadIdx.x & 63;
    if (!lane) r[wid] = p;
    __syncthreads();
    if (threadIdx.x == 0) {
        float l = r[0] + r[1] + r[2] + r[3] + cls_b[0];
        out[b] = 1.f / (1.f + expf(-l));
        out[8 + b] = l;
    }
}

// ---------------------------------------------------------------------------
extern "C" void kernel_launch(void* const* d_in, const int* in_sizes, int n_in,
                              void* d_out, int out_size, void* d_ws, size_t ws_size,
                              hipStream_t stream) {
    const int*   ids     = (const int*)d_in[0];
    const int*   amask   = (const int*)d_in[1];
    const float* tok_emb = (const float*)d_in[2];
    const float* emb_w   = (const float*)d_in[3];
    const float* attn_w  = (const float*)d_in[4];
    const float* Wqkv    = (const float*)d_in[5];
    const float* Wo      = (const float*)d_in[6];
    const float* mlp_w   = (const float*)d_in[7];
    const float* Wi      = (const float*)d_in[8];
    const float* Wmo     = (const float*)d_in[9];
    const float* fin_w   = (const float*)d_in[10];
    const float* cls_w   = (const float*)d_in[11];
    const float* cls_b   = (const float*)d_in[12];
    float* out = (float*)d_out;

    char* wsp = (char*)d_ws;
    size_t off = 0;
    auto alloc = [&](size_t bytes) -> void* {
        void* p = wsp + off;
        off = (off + bytes + 255) & ~(size_t)255;
        return p;
    };
    float* x      = (float*)alloc((size_t)M_ROWS * D_MODEL * 4);
    u16*   hbf    = (u16*)  alloc((size_t)M_ROWS * D_MODEL * 2);
    float* big    = (float*)alloc((size_t)M_ROWS * 2304 * 4);      // qkv / a / xln
    u16*   Qb     = (u16*)  alloc((size_t)96 * S_SEQ * HEAD_D * 2);
    u16*   Kbuf   = (u16*)  alloc((size_t)96 * S_SEQ * HEAD_D * 2);
    u16*   Vt     = (u16*)  alloc((size_t)96 * HEAD_D * S_SEQ * 2);
    u16*   act2   = (u16*)  alloc((size_t)M_ROWS * I_FF * 2);      // attn out / g
    u16*   wT     = (u16*)  alloc((size_t)2304 * 768 * 2);         // WqkvT / WiT
    u16*   wT2    = (u16*)  alloc((size_t)768 * 1152 * 2);         // WoT / WmoT
    float* tabs   = (float*)alloc((size_t)4 * 1024 * 32 * 4);
    float* pooled = (float*)alloc((size_t)8 * D_MODEL * 4);
    float* cg = tabs, *sg = tabs + 32768, *cl = tabs + 65536, *sl = tabs + 98304;

    rope_tables_kernel<<<128, 256, 0, stream>>>(cg, sg, cl, sl);
    embed_ln_kernel<<<M_ROWS, 256, 0, stream>>>(ids, tok_emb, emb_w, x, hbf);

    for (int l = 0; l < L_LAYERS; ++l) {
        int is_global = (l % 3) == 0;
        // ---- attention ----
        transpose_cast_kernel<<<dim3(2304 / 32, 768 / 32), 256, 0, stream>>>(
            Wqkv + (size_t)l * 768 * 2304, wT, 768, 2304);
        if (l > 0)
            ln_kernel<<<M_ROWS, 256, 0, stream>>>(x, attn_w + (size_t)l * 768, hbf, nullptr);
        gemm_nt_kernel<<<dim3(2304 / 128, M_ROWS / 128), 256, 0, stream>>>(
            hbf, wT, nullptr, big, M_ROWS, 2304, 768);
        rope_qk_kernel<<<M_ROWS, 256, 0, stream>>>(big, is_global ? cg : cl,
                                                   is_global ? sg : sl, Qb, Kbuf);
        v_trans_kernel<<<dim3(16, 96), 256, 0, stream>>>(big, Vt);
        flash_attn_kernel<<<dim3(16, 96), 256, 0, stream>>>(Qb, Kbuf, Vt, act2, !is_global);
        transpose_cast_kernel<<<dim3(768 / 32, 768 / 32), 256, 0, stream>>>(
            Wo + (size_t)l * 768 * 768, wT2, 768, 768);
        gemm_nt_kernel<<<dim3(768 / 128, M_ROWS / 128), 256, 0, stream>>>(
            act2, wT2, x, x, M_ROWS, 768, 768);
        // ---- MLP ----
        ln_kernel<<<M_ROWS, 256, 0, stream>>>(x, mlp_w + (size_t)l * 768, hbf, nullptr);
        transpose_cast_kernel<<<dim3(2304 / 32, 768 / 32), 256, 0, stream>>>(
            Wi + (size_t)l * 768 * 2304, wT, 768, 2304);
        gemm_nt_kernel<<<dim3(2304 / 128, M_ROWS / 128), 256, 0, stream>>>(
            hbf, wT, nullptr, big, M_ROWS, 2304, 768);
        geglu_kernel<<<M_ROWS * 288 / 256, 256, 0, stream>>>(big, act2);
        transpose_cast_kernel<<<dim3(768 / 32, 1152 / 32), 256, 0, stream>>>(
            Wmo + (size_t)l * 1152 * 768, wT2, 1152, 768);
        gemm_nt_kernel<<<dim3(768 / 128, M_ROWS / 128), 256, 0, stream>>>(
            act2, wT2, x, x, M_ROWS, 768, 1152);
    }

    // final LN (f32) -> pool -> logits
    ln_kernel<<<M_ROWS, 256, 0, stream>>>(x, fin_w, nullptr, big);
    pool_kernel<<<dim3(3, 8), 256, 0, stream>>>(big, amask, pooled);
    logits_kernel<<<8, 256, 0, stream>>>(pooled, cls_w, cls_b, out);
}

// Round 2
// 7470.014 us; speedup vs baseline: 1.1151x; 1.1151x over previous
//
#include <hip/hip_runtime.h>

typedef unsigned short u16;
typedef __attribute__((ext_vector_type(8))) short short8;      // 8 bf16 MFMA operand
typedef __attribute__((ext_vector_type(8))) unsigned short u16x8;
typedef __attribute__((ext_vector_type(4))) unsigned short u16x4;
typedef __attribute__((ext_vector_type(4))) float floatx4;

#define L_LAYERS 22
#define D_MODEL 768
#define N_HEADS 12
#define HEAD_D 64
#define I_FF 1152
#define B_BATCH 8
#define S_SEQ 1024
#define M_ROWS (B_BATCH * S_SEQ)   // 8192

__device__ __forceinline__ u16 f2bf(float f) {
    union { float f; unsigned u; } v; v.f = f;
    unsigned r = v.u + 0x7fffu + ((v.u >> 16) & 1u);  // RNE
    return (u16)(r >> 16);
}
__device__ __forceinline__ float bf2f(u16 u) {
    union { unsigned u; float f; } v; v.u = ((unsigned)u) << 16;
    return v.f;
}
// async global->LDS, 16B per lane; LDS dest = wave-uniform base + lane*16
__device__ __forceinline__ void gload16(const u16* g, u16* l) {
    __builtin_amdgcn_global_load_lds(
        (const __attribute__((address_space(1))) unsigned int*)g,
        (__attribute__((address_space(3))) unsigned int*)l,
        16, 0, 0);
}

// ---------------------------------------------------------------------------
__global__ __launch_bounds__(256) void rope_tables_kernel(float* cg, float* sg, float* cl, float* sl) {
    int i = blockIdx.x * 256 + threadIdx.x;
    if (i >= 1024 * 32) return;
    int s = i >> 5, j = i & 31;
    float e = (float)(2 * j) / 64.f;
    float fg = (float)s * powf(160000.f, -e);
    float fl = (float)s * powf(10000.f, -e);
    cg[i] = cosf(fg); sg[i] = sinf(fg);
    cl[i] = cosf(fl); sl[i] = sinf(fl);
}

// ---------------------------------------------------------------------------
__global__ __launch_bounds__(256) void embed_ln_kernel(const int* __restrict__ ids,
                                                       const float* __restrict__ emb,
                                                       const float* __restrict__ w,
                                                       float* __restrict__ x,
                                                       u16* __restrict__ hbf) {
    int tok = blockIdx.x;
    int tid = threadIdx.x;
    const float* row = emb + (size_t)ids[tok] * D_MODEL;
    float v[3]; float s = 0.f, q = 0.f;
#pragma unroll
    for (int i = 0; i < 3; ++i) { v[i] = row[tid + 256 * i]; s += v[i]; q += v[i] * v[i]; }
#pragma unroll
    for (int o = 32; o; o >>= 1) { s += __shfl_down(s, o); q += __shfl_down(q, o); }
    __shared__ float rs[4], rq[4];
    int wid = tid >> 6, lane = tid & 63;
    if (!lane) { rs[wid] = s; rq[wid] = q; }
    __syncthreads();
    s = rs[0] + rs[1] + rs[2] + rs[3]; q = rq[0] + rq[1] + rq[2] + rq[3];
    float mean = s * (1.f / 768.f);
    float var = q * (1.f / 768.f) - mean * mean;
    float rstd = rsqrtf(var + 1e-5f);
#pragma unroll
    for (int i = 0; i < 3; ++i) {
        float y = (v[i] - mean) * rstd * w[tid + 256 * i];
        x[(size_t)tok * D_MODEL + tid + 256 * i] = y;
        hbf[(size_t)tok * D_MODEL + tid + 256 * i] = f2bf(y);
    }
}

__global__ __launch_bounds__(256) void ln_kernel(const float* __restrict__ x,
                                                 const float* __restrict__ w,
                                                 u16* __restrict__ out_bf,
                                                 float* __restrict__ out_f32) {
    int tok = blockIdx.x;
    int tid = threadIdx.x;
    const float* row = x + (size_t)tok * D_MODEL;
    float v[3]; float s = 0.f, q = 0.f;
#pragma unroll
    for (int i = 0; i < 3; ++i) { v[i] = row[tid + 256 * i]; s += v[i]; q += v[i] * v[i]; }
#pragma unroll
    for (int o = 32; o; o >>= 1) { s += __shfl_down(s, o); q += __shfl_down(q, o); }
    __shared__ float rs[4], rq[4];
    int wid = tid >> 6, lane = tid & 63;
    if (!lane) { rs[wid] = s; rq[wid] = q; }
    __syncthreads();
    s = rs[0] + rs[1] + rs[2] + rs[3]; q = rq[0] + rq[1] + rq[2] + rq[3];
    float mean = s * (1.f / 768.f);
    float var = q * (1.f / 768.f) - mean * mean;
    float rstd = rsqrtf(var + 1e-5f);
#pragma unroll
    for (int i = 0; i < 3; ++i) {
        float y = (v[i] - mean) * rstd * w[tid + 256 * i];
        if (out_bf)  out_bf[(size_t)tok * D_MODEL + tid + 256 * i] = f2bf(y);
        if (out_f32) out_f32[(size_t)tok * D_MODEL + tid + 256 * i] = y;
    }
}

// ---------------------------------------------------------------------------
__global__ __launch_bounds__(256) void transpose_cast_kernel(const float* __restrict__ in,
                                                             u16* __restrict__ out,
                                                             int Kw, int Nw) {
    __shared__ float tile[32][33];
    int c0 = blockIdx.x * 32, r0 = blockIdx.y * 32;
    int tc = threadIdx.x & 31, tr = threadIdx.x >> 5;
#pragma unroll
    for (int i = 0; i < 4; ++i) {
        int r = tr + i * 8;
        tile[r][tc] = in[(size_t)(r0 + r) * Nw + c0 + tc];
    }
    __syncthreads();
#pragma unroll
    for (int i = 0; i < 4; ++i) {
        int r = tr + i * 8;
        out[(size_t)(c0 + r) * Kw + r0 + tc] = f2bf(tile[tc][r]);
    }
}

// ---------------------------------------------------------------------------
// C(MxN) = A(MxK bf16) @ B(NxK bf16)^T [+ R fp32]; out fp32 or bf16
// m97 structure: 128x128 tile, BK=32, global_load_lds width-16, linear LDS
template<int OUT_BF16>
__global__ __launch_bounds__(256) void gemm_nt_kernel(const u16* __restrict__ A,
                                                      const u16* __restrict__ B,
                                                      const float* __restrict__ R,
                                                      void* __restrict__ Cout,
                                                      int M, int N, int K) {
    __shared__ u16 As[128 * 32];
    __shared__ u16 Bs[128 * 32];
    int tid = threadIdx.x;
    int lane = tid & 63, wid = tid >> 6;
    int uw = __builtin_amdgcn_readfirstlane(wid);
    int lr = lane & 15, lg = lane >> 4;
    int bm = blockIdx.y * 128, bn = blockIdx.x * 128;
    int wr = (wid >> 1) * 64, wc = (wid & 1) * 64;
    floatx4 acc[4][4] = {};
    // staging address: segment seg=uw*2+i covers rows seg*16..seg*16+15, lane->row seg*16+(lane>>2), col (lane&3)*8
    int srow = lane >> 2, scol = (lane & 3) * 8;
    const u16* Abase = A + (size_t)(bm + uw * 32 + srow) * K + scol;
    const u16* Bbase = B + (size_t)(bn + uw * 32 + srow) * K + scol;
    u16* AsSeg = As + uw * 2 * 512;   // 1024B per segment = 512 u16
    u16* BsSeg = Bs + uw * 2 * 512;
    for (int k0 = 0; k0 < K; k0 += 32) {
        __syncthreads();
        gload16(Abase + k0,                    AsSeg);
        gload16(Abase + (size_t)16 * K + k0,   AsSeg + 512);
        gload16(Bbase + k0,                    BsSeg);
        gload16(Bbase + (size_t)16 * K + k0,   BsSeg + 512);
        __syncthreads();
        short8 af[4], bfr[4];
#pragma unroll
        for (int t = 0; t < 4; ++t) {
            af[t]  = *(const short8*)&As[(wr + t * 16 + lr) * 32 + lg * 8];
            bfr[t] = *(const short8*)&Bs[(wc + t * 16 + lr) * 32 + lg * 8];
        }
#pragma unroll
        for (int mi = 0; mi < 4; ++mi)
#pragma unroll
            for (int ni = 0; ni < 4; ++ni)
                acc[mi][ni] = __builtin_amdgcn_mfma_f32_16x16x32_bf16(af[mi], bfr[ni], acc[mi][ni], 0, 0, 0);
    }
#pragma unroll
    for (int mi = 0; mi < 4; ++mi) {
        int m = bm + wr + mi * 16 + lg * 4;
#pragma unroll
        for (int ni = 0; ni < 4; ++ni) {
            int n = bn + wc + ni * 16 + lr;
#pragma unroll
            for (int r = 0; r < 4; ++r) {
                float v = acc[mi][ni][r];
                size_t idx = (size_t)(m + r) * N + n;
                if (R) v += R[idx];
                if (OUT_BF16) ((u16*)Cout)[idx] = f2bf(v);
                else          ((float*)Cout)[idx] = v;
            }
        }
    }
}

// ---------------------------------------------------------------------------
// RoPE from bf16 qkv -> Q,K bf16 [bh][s][d]; vectorized u16x8
__global__ __launch_bounds__(256) void rope_qk_kernel(const u16* __restrict__ qkvb,
                                                      const float* __restrict__ cosT,
                                                      const float* __restrict__ sinT,
                                                      u16* __restrict__ Q,
                                                      u16* __restrict__ K) {
    int linear = blockIdx.x * 256 + threadIdx.x;   // 8192 tok * 96 units
    int tok = linear / 96;
    int rem = linear - tok * 96;
    int qk = rem >> 3 >= 6 ? 1 : 0;                // rem/48
    int hh = (rem >> 2) - qk * 12;                 // (rem/4)%12
    int g = rem & 3;
    int b = tok >> 10, s = tok & 1023;
    const float* ct = cosT + s * 32 + g * 8;
    const float* st = sinT + s * 32 + g * 8;
    const u16* src = qkvb + (size_t)tok * 2304 + qk * 768 + hh * 64 + g * 8;
    u16x8 x1 = *(const u16x8*)src;
    u16x8 x2 = *(const u16x8*)(src + 32);
    u16x8 o1, o2;
#pragma unroll
    for (int j = 0; j < 8; ++j) {
        float c = ct[j], sn = st[j];
        float a = bf2f(x1[j]), bb = bf2f(x2[j]);
        o1[j] = f2bf(a * c - bb * sn);
        o2[j] = f2bf(bb * c + a * sn);
    }
    u16* dst = (qk ? K : Q) + ((size_t)(b * N_HEADS + hh) * S_SEQ + s) * HEAD_D + g * 8;
    *(u16x8*)dst = o1;
    *(u16x8*)(dst + 32) = o2;
}

// V transpose (bf16 in/out): qkv v-part -> Vt [bh][d][s]
__global__ __launch_bounds__(256) void v_trans_kernel(const u16* __restrict__ qkvb,
                                                      u16* __restrict__ Vt) {
    __shared__ u16 t2[64][72];
    int bh = blockIdx.y;
    int b = bh / 12, h = bh - b * 12;
    int s0 = blockIdx.x * 64;
#pragma unroll
    for (int u0 = 0; u0 < 2; ++u0) {
        int u = threadIdx.x + u0 * 256;
        int si = u >> 3, d8 = u & 7;
        u16x8 v = *(const u16x8*)(qkvb + ((size_t)(b * S_SEQ + s0 + si)) * 2304 + 1536 + h * 64 + d8 * 8);
#pragma unroll
        for (int j = 0; j < 8; ++j) t2[d8 * 8 + j][si] = v[j];
    }
    __syncthreads();
#pragma unroll
    for (int u0 = 0; u0 < 2; ++u0) {
        int u = threadIdx.x + u0 * 256;
        int d = u >> 3, s8 = u & 7;
        *(u16x8*)(Vt + ((size_t)bh * 64 + d) * S_SEQ + s0 + s8 * 8) = *(const u16x8*)&t2[d][s8 * 8];
    }
}

// ---------------------------------------------------------------------------
// Flash attention, KVBLK=64, defer-max (T13), setprio (T5)
__global__ __launch_bounds__(256) void flash_attn_kernel(const u16* __restrict__ Q,
                                                         const u16* __restrict__ Kb,
                                                         const u16* __restrict__ Vt,
                                                         u16* __restrict__ O,
                                                         int is_local) {
    __shared__ u16 Pl[4][16][72];
    int bh = blockIdx.y;
    int b = bh / 12, h = bh - b * 12;
    int qb0 = blockIdx.x * 64;
    int tid = threadIdx.x, lane = tid & 63, wid = tid >> 6;
    int lr = lane & 15, lg = lane >> 4;
    int q_row = qb0 + wid * 16 + lr;
    const u16* Qrow = Q + ((size_t)bh * S_SEQ + q_row) * HEAD_D + lg * 8;
    short8 qf0 = *(const short8*)Qrow;
    short8 qf1 = *(const short8*)(Qrow + 32);
    floatx4 accO[4] = {};
    float m_run = -1e30f, l_run = 0.f;
    int kstart = 0, kend = S_SEQ;
    if (is_local) {
        kstart = qb0 >= 64 ? qb0 - 64 : 0;
        kend = qb0 + 128 > S_SEQ ? S_SEQ : qb0 + 128;
    }
    for (int k0 = kstart; k0 < kend; k0 += 64) {
        float sv[16]; float mloc = -1e30f;
        __builtin_amdgcn_s_setprio(1);
#pragma unroll
        for (int g = 0; g < 4; ++g) {
            const u16* Kp = Kb + ((size_t)bh * S_SEQ + k0 + g * 16 + lr) * HEAD_D + lg * 8;
            short8 kf0 = *(const short8*)Kp;
            short8 kf1 = *(const short8*)(Kp + 32);
            floatx4 sg = {};
            sg = __builtin_amdgcn_mfma_f32_16x16x32_bf16(kf0, qf0, sg, 0, 0, 0);
            sg = __builtin_amdgcn_mfma_f32_16x16x32_bf16(kf1, qf1, sg, 0, 0, 0);
#pragma unroll
            for (int r = 0; r < 4; ++r) {
                int kpos = k0 + g * 16 + lg * 4 + r;
                float s1 = sg[r] * 0.125f;
                int dd = q_row - kpos; if (dd < 0) dd = -dd;
                if (is_local && dd > 64) s1 = -1e9f;
                sv[g * 4 + r] = s1; mloc = fmaxf(mloc, s1);
            }
        }
        __builtin_amdgcn_s_setprio(0);
        mloc = fmaxf(mloc, __shfl_xor(mloc, 16));
        mloc = fmaxf(mloc, __shfl_xor(mloc, 32));
        if (!__all(mloc - m_run <= 8.f)) {            // defer-max: rescale only on real growth
            float m_new = fmaxf(m_run, mloc);
            float alpha = __expf(m_run - m_new);
            l_run *= alpha;
#pragma unroll
            for (int c = 0; c < 4; ++c)
#pragma unroll
                for (int r = 0; r < 4; ++r) accO[c][r] *= alpha;
            m_run = m_new;
        }
        float psum = 0.f; u16 pu[16];
#pragma unroll
        for (int i = 0; i < 16; ++i) {
            float p = __expf(sv[i] - m_run);
            psum += p; pu[i] = f2bf(p);
        }
        psum += __shfl_xor(psum, 16);
        psum += __shfl_xor(psum, 32);
        l_run += psum;
#pragma unroll
        for (int g = 0; g < 4; ++g) {
            u16x4 w = { pu[g * 4], pu[g * 4 + 1], pu[g * 4 + 2], pu[g * 4 + 3] };
            *(u16x4*)&Pl[wid][lr][g * 16 + lg * 4] = w;
        }
        asm volatile("s_waitcnt lgkmcnt(0)" ::: "memory");
        __builtin_amdgcn_sched_barrier(0);
        short8 pf0 = *(const short8*)&Pl[wid][lr][lg * 8];
        short8 pf1 = *(const short8*)&Pl[wid][lr][32 + lg * 8];
        __builtin_amdgcn_s_setprio(1);
#pragma unroll
        for (int c = 0; c < 4; ++c) {
            const u16* Vp = Vt + ((size_t)bh * 64 + c * 16 + lr) * S_SEQ + k0 + lg * 8;
            short8 vf0 = *(const short8*)Vp;
            short8 vf1 = *(const short8*)(Vp + 32);
            accO[c] = __builtin_amdgcn_mfma_f32_16x16x32_bf16(vf0, pf0, accO[c], 0, 0, 0);
            accO[c] = __builtin_amdgcn_mfma_f32_16x16x32_bf16(vf1, pf1, accO[c], 0, 0, 0);
        }
        __builtin_amdgcn_s_setprio(0);
    }
    float inv_l = 1.0f / l_run;
#pragma unroll
    for (int c = 0; c < 4; ++c)
#pragma unroll
        for (int r = 0; r < 4; ++r) {
            int d = c * 16 + lg * 4 + r;
            O[((size_t)b * S_SEQ + q_row) * D_MODEL + h * 64 + d] = f2bf(accO[c][r] * inv_l);
        }
}

// ---------------------------------------------------------------------------
// GeGLU from bf16 a -> bf16 g; u16x8 vectorized
__global__ __launch_bounds__(256) void geglu_kernel(const u16* __restrict__ a,
                                                    u16* __restrict__ g) {
    int idx = blockIdx.x * 256 + threadIdx.x;     // unit = 8 elems; 8192*144 units
    int m = idx / 144;
    int i8 = (idx - m * 144) * 8;
    u16x8 xi = *(const u16x8*)(a + (size_t)m * 2304 + i8);
    u16x8 xg = *(const u16x8*)(a + (size_t)m * 2304 + 1152 + i8);
    u16x8 r;
#pragma unroll
    for (int j = 0; j < 8; ++j) {
        float v = bf2f(xi[j]);
        float ge = 0.5f * v * (1.f + erff(v * 0.70710678118654752f));
        r[j] = f2bf(ge * bf2f(xg[j]));
    }
    *(u16x8*)(g + (size_t)m * I_FF + i8) = r;
}

// ---------------------------------------------------------------------------
__global__ __launch_bounds__(256) void pool_kernel(const float* __restrict__ xln,
                                                   const int* __restrict__ amask,
                                                   float* __restrict__ pooled) {
    int b = blockIdx.y;
    int d = blockIdx.x * 256 + threadIdx.x;
    float acc = 0.f, cnt = 0.f;
    for (int s = 0; s < S_SEQ; ++s) {
        float m = (float)amask[b * S_SEQ + s];
        acc += xln[((size_t)b * S_SEQ + s) * D_MODEL + d] * m;
        cnt += m;
    }
    pooled[b * D_MODEL + d] = acc / fmaxf(cnt, 1e-9f);
}

__global__ __launch_bounds__(256) void logits_kernel(const float* __restrict__ pooled,
                                                     const float* __restrict__ cls_w,
                                                     const float* __restrict__ cls_b,
                                                     float* __restrict__ out) {
    int b = blockIdx.x;
    float p = 0.f;
    for (int d = threadIdx.x; d < D_MODEL; d += 256) p += pooled[b * D_MODEL + d] * cls_w[d];
#pragma unroll
    for (int o = 32; o; o >>= 1) p += __shfl_down(p, o);
    __shared__ float r[4];
    int wid = threadIdx.x >> 6, lane = threadIdx.x & 63;
    if (!lane) r[wid] = p;
    __syncthreads();
    if (threadIdx.x == 0) {
        float l = r[0] + r[1] + r[2] + r[3] + cls_b[0];
        out[b] = 1.f / (1.f + expf(-l));
        out[8 + b] = l;
    }
}

// ---------------------------------------------------------------------------
extern "C" void kernel_launch(void* const* d_in, const int* in_sizes, int n_in,
                              void* d_out, int out_size, void* d_ws, size_t ws_size,
                              hipStream_t stream) {
    const int*   ids     = (const int*)d_in[0];
    const int*   amask   = (const int*)d_in[1];
    const float* tok_emb = (const float*)d_in[2];
    const float* emb_w   = (const float*)d_in[3];
    const float* attn_w  = (const float*)d_in[4];
    const float* Wqkv    = (const float*)d_in[5];
    const float* Wo      = (const float*)d_in[6];
    const float* mlp_w   = (const float*)d_in[7];
    const float* Wi      = (const float*)d_in[8];
    const float* Wmo     = (const float*)d_in[9];
    const float* fin_w   = (const float*)d_in[10];
    const float* cls_w   = (const float*)d_in[11];
    const float* cls_b   = (const float*)d_in[12];
    float* out = (float*)d_out;

    char* wsp = (char*)d_ws;
    size_t off = 0;
    auto alloc = [&](size_t bytes) -> void* {
        void* p = wsp + off;
        off = (off + bytes + 255) & ~(size_t)255;
        return p;
    };
    float* x      = (float*)alloc((size_t)M_ROWS * D_MODEL * 4);
    u16*   hbf    = (u16*)  alloc((size_t)M_ROWS * D_MODEL * 2);
    u16*   qkvb   = (u16*)  alloc((size_t)M_ROWS * 2304 * 2);     // qkv bf16 / a bf16
    u16*   Qb     = (u16*)  alloc((size_t)96 * S_SEQ * HEAD_D * 2);
    u16*   Kbuf   = (u16*)  alloc((size_t)96 * S_SEQ * HEAD_D * 2);
    u16*   Vt     = (u16*)  alloc((size_t)96 * HEAD_D * S_SEQ * 2);
    u16*   act2   = (u16*)  alloc((size_t)M_ROWS * I_FF * 2);     // attn out / g
    u16*   wT     = (u16*)  alloc((size_t)2304 * 768 * 2);        // WqkvT / WiT
    u16*   wT2    = (u16*)  alloc((size_t)768 * 1152 * 2);        // WoT / WmoT
    float* xln    = (float*)alloc((size_t)M_ROWS * D_MODEL * 4);
    float* tabs   = (float*)alloc((size_t)4 * 1024 * 32 * 4);
    float* pooled = (float*)alloc((size_t)8 * D_MODEL * 4);
    float* cg = tabs, *sg = tabs + 32768, *cl = tabs + 65536, *sl = tabs + 98304;

    rope_tables_kernel<<<128, 256, 0, stream>>>(cg, sg, cl, sl);
    embed_ln_kernel<<<M_ROWS, 256, 0, stream>>>(ids, tok_emb, emb_w, x, hbf);

    for (int l = 0; l < L_LAYERS; ++l) {
        int is_global = (l % 3) == 0;
        // ---- attention ----
        transpose_cast_kernel<<<dim3(2304 / 32, 768 / 32), 256, 0, stream>>>(
            Wqkv + (size_t)l * 768 * 2304, wT, 768, 2304);
        if (l > 0)
            ln_kernel<<<M_ROWS, 256, 0, stream>>>(x, attn_w + (size_t)l * 768, hbf, nullptr);
        gemm_nt_kernel<1><<<dim3(2304 / 128, M_ROWS / 128), 256, 0, stream>>>(
            hbf, wT, nullptr, qkvb, M_ROWS, 2304, 768);
        rope_qk_kernel<<<M_ROWS * 96 / 256, 256, 0, stream>>>(qkvb, is_global ? cg : cl,
                                                              is_global ? sg : sl, Qb, Kbuf);
        v_trans_kernel<<<dim3(16, 96), 256, 0, stream>>>(qkvb, Vt);
        flash_attn_kernel<<<dim3(16, 96), 256, 0, stream>>>(Qb, Kbuf, Vt, act2, !is_global);
        transpose_cast_kernel<<<dim3(768 / 32, 768 / 32), 256, 0, stream>>>(
            Wo + (size_t)l * 768 * 768, wT2, 768, 768);
        gemm_nt_kernel<0><<<dim3(768 / 128, M_ROWS / 128), 256, 0, stream>>>(
            act2, wT2, x, x, M_ROWS, 768, 768);
        // ---- MLP ----
        ln_kernel<<<M_ROWS, 256, 0, stream>>>(x, mlp_w + (size_t)l * 768, hbf, nullptr);
        transpose_cast_kernel<<<dim3(2304 / 32, 768 / 32), 256, 0, stream>>>(
            Wi + (size_t)l * 768 * 2304, wT, 768, 2304);
        gemm_nt_kernel<1><<<dim3(2304 / 128, M_ROWS / 128), 256, 0, stream>>>(
            hbf, wT, nullptr, qkvb, M_ROWS, 2304, 768);
        geglu_kernel<<<M_ROWS * 144 / 256, 256, 0, stream>>>(qkvb, act2);
        transpose_cast_kernel<<<dim3(768 / 32, 1152 / 32), 256, 0, stream>>>(
            Wmo + (size_t)l * 1152 * 768, wT2, 1152, 768);
        gemm_nt_kernel<0><<<dim3(768 / 128, M_ROWS / 128), 256, 0, stream>>>(
            act2, wT2, x, x, M_ROWS, 768, 1152);
    }

    ln_kernel<<<M_ROWS, 256, 0, stream>>>(x, fin_w, nullptr, xln);
    pool_kernel<<<dim3(3, 8), 256, 0, stream>>>(xln, amask, pooled);
    logits_kernel<<<8, 256, 0, stream>>>(pooled, cls_w, cls_b, out);
}

// Round 3
// 5790.637 us; speedup vs baseline: 1.4385x; 1.2900x over previous
//
#include <hip/hip_runtime.h>

typedef unsigned short u16;
typedef __attribute__((ext_vector_type(8))) short short8;      // 8 bf16 MFMA operand
typedef __attribute__((ext_vector_type(8))) unsigned short u16x8;
typedef __attribute__((ext_vector_type(4))) unsigned short u16x4;
typedef __attribute__((ext_vector_type(4))) float floatx4;

#define L_LAYERS 22
#define D_MODEL 768
#define N_HEADS 12
#define HEAD_D 64
#define I_FF 1152
#define B_BATCH 8
#define S_SEQ 1024
#define M_ROWS (B_BATCH * S_SEQ)   // 8192

__device__ __forceinline__ u16 f2bf(float f) {
    union { float f; unsigned u; } v; v.f = f;
    unsigned r = v.u + 0x7fffu + ((v.u >> 16) & 1u);  // RNE
    return (u16)(r >> 16);
}
__device__ __forceinline__ float bf2f(u16 u) {
    union { unsigned u; float f; } v; v.u = ((unsigned)u) << 16;
    return v.f;
}
__device__ __forceinline__ void gload16(const u16* g, u16* l) {
    __builtin_amdgcn_global_load_lds(
        (const __attribute__((address_space(1))) unsigned int*)g,
        (__attribute__((address_space(3))) unsigned int*)l,
        16, 0, 0);
}

// ---------------------------------------------------------------------------
__global__ __launch_bounds__(256) void rope_tables_kernel(float* cg, float* sg, float* cl, float* sl) {
    int i = blockIdx.x * 256 + threadIdx.x;
    if (i >= 1024 * 32) return;
    int s = i >> 5, j = i & 31;
    float e = (float)(2 * j) / 64.f;
    float fg = (float)s * powf(160000.f, -e);
    float fl = (float)s * powf(10000.f, -e);
    cg[i] = cosf(fg); sg[i] = sinf(fg);
    cl[i] = cosf(fl); sl[i] = sinf(fl);
}

// ---------------------------------------------------------------------------
__global__ __launch_bounds__(256) void embed_ln_kernel(const int* __restrict__ ids,
                                                       const float* __restrict__ emb,
                                                       const float* __restrict__ w,
                                                       float* __restrict__ x,
                                                       u16* __restrict__ hbf) {
    int tok = blockIdx.x;
    int tid = threadIdx.x;
    const float* row = emb + (size_t)ids[tok] * D_MODEL;
    float v[3]; float s = 0.f, q = 0.f;
#pragma unroll
    for (int i = 0; i < 3; ++i) { v[i] = row[tid + 256 * i]; s += v[i]; q += v[i] * v[i]; }
#pragma unroll
    for (int o = 32; o; o >>= 1) { s += __shfl_down(s, o); q += __shfl_down(q, o); }
    __shared__ float rs[4], rq[4];
    int wid = tid >> 6, lane = tid & 63;
    if (!lane) { rs[wid] = s; rq[wid] = q; }
    __syncthreads();
    s = rs[0] + rs[1] + rs[2] + rs[3]; q = rq[0] + rq[1] + rq[2] + rq[3];
    float mean = s * (1.f / 768.f);
    float var = q * (1.f / 768.f) - mean * mean;
    float rstd = rsqrtf(var + 1e-5f);
#pragma unroll
    for (int i = 0; i < 3; ++i) {
        float y = (v[i] - mean) * rstd * w[tid + 256 * i];
        x[(size_t)tok * D_MODEL + tid + 256 * i] = y;
        hbf[(size_t)tok * D_MODEL + tid + 256 * i] = f2bf(y);
    }
}

__global__ __launch_bounds__(256) void ln_kernel(const float* __restrict__ x,
                                                 const float* __restrict__ w,
                                                 u16* __restrict__ out_bf,
                                                 float* __restrict__ out_f32) {
    int tok = blockIdx.x;
    int tid = threadIdx.x;
    const float* row = x + (size_t)tok * D_MODEL;
    float v[3]; float s = 0.f, q = 0.f;
#pragma unroll
    for (int i = 0; i < 3; ++i) { v[i] = row[tid + 256 * i]; s += v[i]; q += v[i] * v[i]; }
#pragma unroll
    for (int o = 32; o; o >>= 1) { s += __shfl_down(s, o); q += __shfl_down(q, o); }
    __shared__ float rs[4], rq[4];
    int wid = tid >> 6, lane = tid & 63;
    if (!lane) { rs[wid] = s; rq[wid] = q; }
    __syncthreads();
    s = rs[0] + rs[1] + rs[2] + rs[3]; q = rq[0] + rq[1] + rq[2] + rq[3];
    float mean = s * (1.f / 768.f);
    float var = q * (1.f / 768.f) - mean * mean;
    float rstd = rsqrtf(var + 1e-5f);
#pragma unroll
    for (int i = 0; i < 3; ++i) {
        float y = (v[i] - mean) * rstd * w[tid + 256 * i];
        if (out_bf)  out_bf[(size_t)tok * D_MODEL + tid + 256 * i] = f2bf(y);
        if (out_f32) out_f32[(size_t)tok * D_MODEL + tid + 256 * i] = y;
    }
}

// ---------------------------------------------------------------------------
// one dispatch converts all 4 weights of a layer; z selects which
// z=0: Wqkv (768x2304) -> qkvT (2304x768)
// z=1: Wo   (768x768)  -> woT  (768x768)
// z=2: Wi   (768x2304) -> wiT  PERMUTED rows (inp/gate interleave by 16)
// z=3: Wmo  (1152x768) -> wmoT (768x1152)
__global__ __launch_bounds__(256) void weight_prep_kernel(const float* __restrict__ Wqkv,
                                                          const float* __restrict__ Wo,
                                                          const float* __restrict__ Wi,
                                                          const float* __restrict__ Wmo,
                                                          u16* __restrict__ qkvT,
                                                          u16* __restrict__ woT,
                                                          u16* __restrict__ wiT,
                                                          u16* __restrict__ wmoT) {
    __shared__ float tile[32][33];
    int z = blockIdx.z;
    const float* in; u16* out; int Kw, Nw, perm = 0;
    if (z == 0)      { in = Wqkv; out = qkvT; Kw = 768;  Nw = 2304; }
    else if (z == 1) { in = Wo;   out = woT;  Kw = 768;  Nw = 768;  }
    else if (z == 2) { in = Wi;   out = wiT;  Kw = 768;  Nw = 2304; perm = 1; }
    else             { in = Wmo;  out = wmoT; Kw = 1152; Nw = 768;  }
    int c0 = blockIdx.x * 32, r0 = blockIdx.y * 32;
    if (c0 >= Nw || r0 >= Kw) return;
    int tc = threadIdx.x & 31, tr = threadIdx.x >> 5;
#pragma unroll
    for (int i = 0; i < 4; ++i) {
        int r = tr + i * 8;
        tile[r][tc] = in[(size_t)(r0 + r) * Nw + c0 + tc];
    }
    __syncthreads();
#pragma unroll
    for (int i = 0; i < 4; ++i) {
        int cc = c0 + tr + i * 8;          // source col = dest row (pre-perm)
        int prow = cc;
        if (perm) {
            if (cc < 1152) prow = ((cc >> 4) << 5) + (cc & 15);
            else { int j = cc - 1152; prow = ((j >> 4) << 5) + 16 + (j & 15); }
        }
        out[(size_t)prow * Kw + r0 + tc] = f2bf(tile[tc][tr + i * 8]);
    }
}

// ---------------------------------------------------------------------------
// C(MxN) = A(MxK bf16) @ B(NxK bf16)^T ; m97-structure main loop
// MODE 0: f32 out (+R residual)
// MODE 2: fused RoPE epilogue -> Q,K [bh][s][d] bf16, V -> Vc [bh][s][d] bf16
// MODE 3: fused GeGLU epilogue (permuted WiT) -> g bf16 [m][1152]
template<int MODE>
__global__ __launch_bounds__(256) void gemm_nt_kernel(const u16* __restrict__ A,
                                                      const u16* __restrict__ B,
                                                      const float* __restrict__ R,
                                                      void* __restrict__ Cout,
                                                      int M, int N, int K,
                                                      const float* __restrict__ cosT,
                                                      const float* __restrict__ sinT,
                                                      u16* __restrict__ Qo,
                                                      u16* __restrict__ Ko,
                                                      u16* __restrict__ Vc) {
    __shared__ u16 As[128 * 32];
    __shared__ u16 Bs[128 * 32];
    int tid = threadIdx.x;
    int lane = tid & 63, wid = tid >> 6;
    int uw = __builtin_amdgcn_readfirstlane(wid);
    int lr = lane & 15, lg = lane >> 4;
    int bm = blockIdx.y * 128, bn = blockIdx.x * 128;
    int wr = (wid >> 1) * 64, wc = (wid & 1) * 64;
    floatx4 acc[4][4] = {};
    int srow = lane >> 2, scol = (lane & 3) * 8;
    const u16* Abase = A + (size_t)(bm + uw * 32 + srow) * K + scol;
    const u16* Bbase = B + (size_t)(bn + uw * 32 + srow) * K + scol;
    u16* AsSeg = As + uw * 2 * 512;
    u16* BsSeg = Bs + uw * 2 * 512;
    for (int k0 = 0; k0 < K; k0 += 32) {
        __syncthreads();
        gload16(Abase + k0,                  AsSeg);
        gload16(Abase + (size_t)16 * K + k0, AsSeg + 512);
        gload16(Bbase + k0,                  BsSeg);
        gload16(Bbase + (size_t)16 * K + k0, BsSeg + 512);
        __syncthreads();
        short8 af[4], bfr[4];
#pragma unroll
        for (int t = 0; t < 4; ++t) {
            af[t]  = *(const short8*)&As[(wr + t * 16 + lr) * 32 + lg * 8];
            bfr[t] = *(const short8*)&Bs[(wc + t * 16 + lr) * 32 + lg * 8];
        }
#pragma unroll
        for (int mi = 0; mi < 4; ++mi)
#pragma unroll
            for (int ni = 0; ni < 4; ++ni)
                acc[mi][ni] = __builtin_amdgcn_mfma_f32_16x16x32_bf16(af[mi], bfr[ni], acc[mi][ni], 0, 0, 0);
    }

    if (MODE == 0) {
#pragma unroll
        for (int mi = 0; mi < 4; ++mi) {
            int m = bm + wr + mi * 16 + lg * 4;
#pragma unroll
            for (int ni = 0; ni < 4; ++ni) {
                int n = bn + wc + ni * 16 + lr;
#pragma unroll
                for (int r = 0; r < 4; ++r) {
                    float v = acc[mi][ni][r];
                    size_t idx = (size_t)(m + r) * N + n;
                    if (R) v += R[idx];
                    ((float*)Cout)[idx] = v;
                }
            }
        }
    }
    if (MODE == 2) {
        int nb = bn + wc;                    // 64-aligned wave col base
        int which = nb / 768;                // 0=q 1=k 2=v
        int h = (nb - which * 768) >> 6;
        if (which < 2) {
            u16* Out = which ? Ko : Qo;
#pragma unroll
            for (int mi = 0; mi < 4; ++mi)
#pragma unroll
                for (int r = 0; r < 4; ++r) {
                    int m = bm + wr + mi * 16 + lg * 4 + r;
                    int s = m & 1023, b = m >> 10;
                    size_t base = ((size_t)(b * N_HEADS + h) * S_SEQ + s) * HEAD_D;
#pragma unroll
                    for (int ni = 0; ni < 2; ++ni) {
                        int j = ni * 16 + lr;                 // j in [0,32)
                        float c = cosT[s * 32 + j], sn = sinT[s * 32 + j];
                        float q1 = acc[mi][ni][r], q2 = acc[mi][ni + 2][r];
                        Out[base + j]      = f2bf(q1 * c - q2 * sn);
                        Out[base + j + 32] = f2bf(q2 * c + q1 * sn);
                    }
                }
        } else {
#pragma unroll
            for (int mi = 0; mi < 4; ++mi)
#pragma unroll
                for (int r = 0; r < 4; ++r) {
                    int m = bm + wr + mi * 16 + lg * 4 + r;
                    int s = m & 1023, b = m >> 10;
                    size_t base = ((size_t)(b * N_HEADS + h) * S_SEQ + s) * HEAD_D;
#pragma unroll
                    for (int ni = 0; ni < 4; ++ni)
                        Vc[base + ni * 16 + lr] = f2bf(acc[mi][ni][r]);
                }
        }
    }
    if (MODE == 3) {
        int t0 = (bn + wc) >> 5;            // 32-col group index
#pragma unroll
        for (int mi = 0; mi < 4; ++mi)
#pragma unroll
            for (int r = 0; r < 4; ++r) {
                int m = bm + wr + mi * 16 + lg * 4 + r;
#pragma unroll
                for (int p = 0; p < 2; ++p) {
                    float vi = acc[mi][2 * p][r];
                    float vg = acc[mi][2 * p + 1][r];
                    float ge = 0.5f * vi * (1.f + erff(vi * 0.70710678118654752f));
                    ((u16*)Cout)[(size_t)m * I_FF + (t0 + p) * 16 + lr] = f2bf(ge * vg);
                }
            }
    }
}

// ---------------------------------------------------------------------------
// V transpose: Vc [bh][s][d] -> Vt [bh][d][s]
__global__ __launch_bounds__(256) void v_trans_kernel(const u16* __restrict__ Vc,
                                                      u16* __restrict__ Vt) {
    __shared__ u16 t2[64][72];
    int bh = blockIdx.y;
    int s0 = blockIdx.x * 64;
#pragma unroll
    for (int u0 = 0; u0 < 2; ++u0) {
        int u = threadIdx.x + u0 * 256;
        int si = u >> 3, d8 = (u & 7) * 8;
        u16x8 v = *(const u16x8*)(Vc + ((size_t)bh * S_SEQ + s0 + si) * HEAD_D + d8);
#pragma unroll
        for (int j = 0; j < 8; ++j) t2[d8 + j][si] = v[j];
    }
    __syncthreads();
#pragma unroll
    for (int u0 = 0; u0 < 2; ++u0) {
        int u = threadIdx.x + u0 * 256;
        int d = u >> 3, s8 = (u & 7) * 8;
        *(u16x8*)(Vt + ((size_t)bh * HEAD_D + d) * S_SEQ + s0 + s8) = *(const u16x8*)&t2[d][s8];
    }
}

// ---------------------------------------------------------------------------
// Flash attention: LDS-staged K,V tiles (shared by 4 waves), T14 async split,
// KVBLK=64, defer-max, setprio
__global__ __launch_bounds__(256) void flash_attn_kernel(const u16* __restrict__ Q,
                                                         const u16* __restrict__ Kb,
                                                         const u16* __restrict__ Vt,
                                                         u16* __restrict__ O,
                                                         int is_local) {
    __shared__ u16 Ks[64][72];
    __shared__ u16 Vs[64][72];
    __shared__ u16 Pl[4][16][72];
    int bh = blockIdx.y;
    int b = bh / 12, h = bh - b * 12;
    int qb0 = blockIdx.x * 64;
    int tid = threadIdx.x, lane = tid & 63, wid = tid >> 6;
    int lr = lane & 15, lg = lane >> 4;
    int q_row = qb0 + wid * 16 + lr;
    const u16* Qrow = Q + ((size_t)bh * S_SEQ + q_row) * HEAD_D + lg * 8;
    short8 qf0 = *(const short8*)Qrow;
    short8 qf1 = *(const short8*)(Qrow + 32);
    floatx4 accO[4] = {};
    float m_run = -1e30f, l_run = 0.f;
    int kstart = 0, kend = S_SEQ;
    if (is_local) {
        kstart = qb0 >= 64 ? qb0 - 64 : 0;
        kend = qb0 + 128 > S_SEQ ? S_SEQ : qb0 + 128;
    }
    int nt = (kend - kstart) >> 6;
    u16x8 kreg[2], vreg[2];
    int su_r = tid >> 3, su_c = (tid & 7) * 8;          // unit 0 mapping
    int su_r2 = (tid + 256) >> 3;                       // unit 1 (same su_c)
    {
        int k0 = kstart;
        kreg[0] = *(const u16x8*)(Kb + ((size_t)bh * S_SEQ + k0 + su_r) * HEAD_D + su_c);
        vreg[0] = *(const u16x8*)(Vt + ((size_t)bh * HEAD_D + su_r) * S_SEQ + k0 + su_c);
        kreg[1] = *(const u16x8*)(Kb + ((size_t)bh * S_SEQ + k0 + su_r2) * HEAD_D + su_c);
        vreg[1] = *(const u16x8*)(Vt + ((size_t)bh * HEAD_D + su_r2) * S_SEQ + k0 + su_c);
    }
    for (int t = 0; t < nt; ++t) {
        int k0 = kstart + (t << 6);
        if (t) __syncthreads();             // prior tile compute done
        *(u16x8*)&Ks[su_r][su_c]  = kreg[0];
        *(u16x8*)&Vs[su_r][su_c]  = vreg[0];
        *(u16x8*)&Ks[su_r2][su_c] = kreg[1];
        *(u16x8*)&Vs[su_r2][su_c] = vreg[1];
        if (t + 1 < nt) {                   // issue next tile loads; latency hides under compute
            int kn = k0 + 64;
            kreg[0] = *(const u16x8*)(Kb + ((size_t)bh * S_SEQ + kn + su_r) * HEAD_D + su_c);
            vreg[0] = *(const u16x8*)(Vt + ((size_t)bh * HEAD_D + su_r) * S_SEQ + kn + su_c);
            kreg[1] = *(const u16x8*)(Kb + ((size_t)bh * S_SEQ + kn + su_r2) * HEAD_D + su_c);
            vreg[1] = *(const u16x8*)(Vt + ((size_t)bh * HEAD_D + su_r2) * S_SEQ + kn + su_c);
        }
        __syncthreads();                    // staged tile visible
        float sv[16]; float mloc = -1e30f;
        __builtin_amdgcn_s_setprio(1);
#pragma unroll
        for (int g = 0; g < 4; ++g) {
            short8 kf0 = *(const short8*)&Ks[g * 16 + lr][lg * 8];
            short8 kf1 = *(const short8*)&Ks[g * 16 + lr][lg * 8 + 32];
            floatx4 sg0 = {};
            sg0 = __builtin_amdgcn_mfma_f32_16x16x32_bf16(kf0, qf0, sg0, 0, 0, 0);
            sg0 = __builtin_amdgcn_mfma_f32_16x16x32_bf16(kf1, qf1, sg0, 0, 0, 0);
#pragma unroll
            for (int r = 0; r < 4; ++r) {
                int kpos = k0 + g * 16 + lg * 4 + r;
                float s1 = sg0[r] * 0.125f;
                int dd = q_row - kpos; if (dd < 0) dd = -dd;
                if (is_local && dd > 64) s1 = -1e9f;
                sv[g * 4 + r] = s1; mloc = fmaxf(mloc, s1);
            }
        }
        __builtin_amdgcn_s_setprio(0);
        mloc = fmaxf(mloc, __shfl_xor(mloc, 16));
        mloc = fmaxf(mloc, __shfl_xor(mloc, 32));
        if (!__all(mloc - m_run <= 8.f)) {
            float m_new = fmaxf(m_run, mloc);
            float alpha = __expf(m_run - m_new);
            l_run *= alpha;
#pragma unroll
            for (int c = 0; c < 4; ++c)
#pragma unroll
                for (int r = 0; r < 4; ++r) accO[c][r] *= alpha;
            m_run = m_new;
        }
        float psum = 0.f; u16 pu[16];
#pragma unroll
        for (int i = 0; i < 16; ++i) {
            float p = __expf(sv[i] - m_run);
            psum += p; pu[i] = f2bf(p);
        }
        psum += __shfl_xor(psum, 16);
        psum += __shfl_xor(psum, 32);
        l_run += psum;
#pragma unroll
        for (int g = 0; g < 4; ++g) {
            u16x4 w = { pu[g * 4], pu[g * 4 + 1], pu[g * 4 + 2], pu[g * 4 + 3] };
            *(u16x4*)&Pl[wid][lr][g * 16 + lg * 4] = w;
        }
        asm volatile("s_waitcnt lgkmcnt(0)" ::: "memory");
        __builtin_amdgcn_sched_barrier(0);
        short8 pf0 = *(const short8*)&Pl[wid][lr][lg * 8];
        short8 pf1 = *(const short8*)&Pl[wid][lr][32 + lg * 8];
        __builtin_amdgcn_s_setprio(1);
#pragma unroll
        for (int c = 0; c < 4; ++c) {
            short8 vf0 = *(const short8*)&Vs[c * 16 + lr][lg * 8];
            short8 vf1 = *(const short8*)&Vs[c * 16 + lr][lg * 8 + 32];
            accO[c] = __builtin_amdgcn_mfma_f32_16x16x32_bf16(vf0, pf0, accO[c], 0, 0, 0);
            accO[c] = __builtin_amdgcn_mfma_f32_16x16x32_bf16(vf1, pf1, accO[c], 0, 0, 0);
        }
        __builtin_amdgcn_s_setprio(0);
    }
    float inv_l = 1.0f / l_run;
#pragma unroll
    for (int c = 0; c < 4; ++c)
#pragma unroll
        for (int r = 0; r < 4; ++r) {
            int d = c * 16 + lg * 4 + r;
            O[((size_t)b * S_SEQ + q_row) * D_MODEL + h * 64 + d] = f2bf(accO[c][r] * inv_l);
        }
}

// ---------------------------------------------------------------------------
__global__ __launch_bounds__(256) void pool_kernel(const float* __restrict__ xln,
                                                   const int* __restrict__ amask,
                                                   float* __restrict__ pooled) {
    int b = blockIdx.y;
    int d = blockIdx.x * 256 + threadIdx.x;
    float acc = 0.f, cnt = 0.f;
    for (int s = 0; s < S_SEQ; ++s) {
        float m = (float)amask[b * S_SEQ + s];
        acc += xln[((size_t)b * S_SEQ + s) * D_MODEL + d] * m;
        cnt += m;
    }
    pooled[b * D_MODEL + d] = acc / fmaxf(cnt, 1e-9f);
}

__global__ __launch_bounds__(256) void logits_kernel(const float* __restrict__ pooled,
                                                     const float* __restrict__ cls_w,
                                                     const float* __restrict__ cls_b,
                                                     float* __restrict__ out) {
    int b = blockIdx.x;
    float p = 0.f;
    for (int d = threadIdx.x; d < D_MODEL; d += 256) p += pooled[b * D_MODEL + d] * cls_w[d];
#pragma unroll
    for (int o = 32; o; o >>= 1) p += __shfl_down(p, o);
    __shared__ float r[4];
    int wid = threadIdx.x >> 6, lane = threadIdx.x & 63;
    if (!lane) r[wid] = p;
    __syncthreads();
    if (threadIdx.x == 0) {
        float l = r[0] + r[1] + r[2] + r[3] + cls_b[0];
        out[b] = 1.f / (1.f + expf(-l));
        out[8 + b] = l;
    }
}

// ---------------------------------------------------------------------------
extern "C" void kernel_launch(void* const* d_in, const int* in_sizes, int n_in,
                              void* d_out, int out_size, void* d_ws, size_t ws_size,
                              hipStream_t stream) {
    const int*   ids     = (const int*)d_in[0];
    const int*   amask   = (const int*)d_in[1];
    const float* tok_emb = (const float*)d_in[2];
    const float* emb_w   = (const float*)d_in[3];
    const float* attn_w  = (const float*)d_in[4];
    const float* Wqkv    = (const float*)d_in[5];
    const float* Wo      = (const float*)d_in[6];
    const float* mlp_w   = (const float*)d_in[7];
    const float* Wi      = (const float*)d_in[8];
    const float* Wmo     = (const float*)d_in[9];
    const float* fin_w   = (const float*)d_in[10];
    const float* cls_w   = (const float*)d_in[11];
    const float* cls_b   = (const float*)d_in[12];
    float* out = (float*)d_out;

    char* wsp = (char*)d_ws;
    size_t off = 0;
    auto alloc = [&](size_t bytes) -> void* {
        void* p = wsp + off;
        off = (off + bytes + 255) & ~(size_t)255;
        return p;
    };
    float* x      = (float*)alloc((size_t)M_ROWS * D_MODEL * 4);
    u16*   hbf    = (u16*)  alloc((size_t)M_ROWS * D_MODEL * 2);
    u16*   Qb     = (u16*)  alloc((size_t)96 * S_SEQ * HEAD_D * 2);
    u16*   Kbuf   = (u16*)  alloc((size_t)96 * S_SEQ * HEAD_D * 2);
    u16*   Vc     = (u16*)  alloc((size_t)96 * S_SEQ * HEAD_D * 2);
    u16*   Vt     = (u16*)  alloc((size_t)96 * HEAD_D * S_SEQ * 2);
    u16*   act2   = (u16*)  alloc((size_t)M_ROWS * I_FF * 2);     // attn out / g
    u16*   qkvT   = (u16*)  alloc((size_t)2304 * 768 * 2);
    u16*   woT    = (u16*)  alloc((size_t)768 * 768 * 2);
    u16*   wiT    = (u16*)  alloc((size_t)2304 * 768 * 2);
    u16*   wmoT   = (u16*)  alloc((size_t)768 * 1152 * 2);
    float* xln    = (float*)alloc((size_t)M_ROWS * D_MODEL * 4);
    float* tabs   = (float*)alloc((size_t)4 * 1024 * 32 * 4);
    float* pooled = (float*)alloc((size_t)8 * D_MODEL * 4);
    float* cg = tabs, *sg = tabs + 32768, *cl = tabs + 65536, *sl = tabs + 98304;

    rope_tables_kernel<<<128, 256, 0, stream>>>(cg, sg, cl, sl);
    embed_ln_kernel<<<M_ROWS, 256, 0, stream>>>(ids, tok_emb, emb_w, x, hbf);

    for (int l = 0; l < L_LAYERS; ++l) {
        int is_global = (l % 3) == 0;
        const float* cosT = is_global ? cg : cl;
        const float* sinT = is_global ? sg : sl;
        // all 4 weight transposes in one dispatch
        weight_prep_kernel<<<dim3(72, 36, 4), 256, 0, stream>>>(
            Wqkv + (size_t)l * 768 * 2304, Wo + (size_t)l * 768 * 768,
            Wi + (size_t)l * 768 * 2304, Wmo + (size_t)l * 1152 * 768,
            qkvT, woT, wiT, wmoT);
        // ---- attention ----
        if (l > 0)
            ln_kernel<<<M_ROWS, 256, 0, stream>>>(x, attn_w + (size_t)l * 768, hbf, nullptr);
        gemm_nt_kernel<2><<<dim3(2304 / 128, M_ROWS / 128), 256, 0, stream>>>(
            hbf, qkvT, nullptr, nullptr, M_ROWS, 2304, 768, cosT, sinT, Qb, Kbuf, Vc);
        v_trans_kernel<<<dim3(16, 96), 256, 0, stream>>>(Vc, Vt);
        flash_attn_kernel<<<dim3(16, 96), 256, 0, stream>>>(Qb, Kbuf, Vt, act2, !is_global);
        gemm_nt_kernel<0><<<dim3(768 / 128, M_ROWS / 128), 256, 0, stream>>>(
            act2, woT, x, x, M_ROWS, 768, 768, nullptr, nullptr, nullptr, nullptr, nullptr);
        // ---- MLP ----
        ln_kernel<<<M_ROWS, 256, 0, stream>>>(x, mlp_w + (size_t)l * 768, hbf, nullptr);
        gemm_nt_kernel<3><<<dim3(2304 / 128, M_ROWS / 128), 256, 0, stream>>>(
            hbf, wiT, nullptr, act2, M_ROWS, 2304, 768, nullptr, nullptr, nullptr, nullptr, nullptr);
        gemm_nt_kernel<0><<<dim3(768 / 128, M_ROWS / 128), 256, 0, stream>>>(
            act2, wmoT, x, x, M_ROWS, 768, 1152, nullptr, nullptr, nullptr, nullptr, nullptr);
    }

    ln_kernel<<<M_ROWS, 256, 0, stream>>>(x, fin_w, nullptr, xln);
    pool_kernel<<<dim3(3, 8), 256, 0, stream>>>(xln, amask, pooled);
    logits_kernel<<<8, 256, 0, stream>>>(pooled, cls_w, cls_b, out);
}